// Round 8
// baseline (176.727 us; speedup 1.0000x reference)
//
#include <hip/hip_runtime.h>

// Problem constants: B=1024, D=64, K=512, L=64 (h*w=8*8)
// x:        (B,D,L)   b*4096 + d*64 + l
// emb/dw:   (D,K,L)   d*32768 + k*64 + l
// eT:       (L,K,D)   (l*512 + k)*64 + d
// e2T:      (L,K)     l*512 + k
// countsT:  (L,K)     l*512 + k   (exact integer counts as float, via f32 atomics)
// dwT:      (K,L,D)   (k*64 + l)*64 + d
// xT:       (L,B,D)   (l*1024 + b)*64 + d  -- emitted by kargmin into out_enc region;
//                     read by kdw; overwritten by kgather (later kernel) -- no race.
// idxb:     (B,L), idxT: (L,B)

typedef float f32x4 __attribute__((ext_vector_type(4)));

// ---------------- K1: emb transpose + e2 + zero counts/loss ----------------
__global__ __launch_bounds__(256) void ktransE(const float* __restrict__ emb,
                                               float* __restrict__ eT,
                                               float* __restrict__ e2T,
                                               float* __restrict__ countsT,
                                               double* __restrict__ lossAcc) {
  const int k = blockIdx.x;
  const int t = threadIdx.x;
  __shared__ float s[64][65];
#pragma unroll
  for (int i = 0; i < 16; ++i) {
    int e = t + i * 256;
    int d = e >> 6, l = e & 63;
    s[d][l] = emb[d * 32768 + k * 64 + l];
  }
  __syncthreads();
  if (t < 64) {
    float s2 = 0.f;
#pragma unroll
    for (int d = 0; d < 64; ++d) {
      float v = s[d][t];
      s2 = __fadd_rn(s2, __fmul_rn(v, v));  // round(v*v), sequential-d sum like ref
    }
    e2T[t * 512 + k] = s2;
    countsT[k * 64 + t] = 0.f;   // all 32768 entries zeroed across 512 blocks
  }
  if (k == 0 && t == 0) lossAcc[0] = 0.0;
#pragma unroll
  for (int i = 0; i < 4; ++i) {
    int j = t + i * 256;
    int l = j >> 4, d0 = (j & 15) * 4;
    float4 w;
    w.x = s[d0][l]; w.y = s[d0 + 1][l]; w.z = s[d0 + 2][l]; w.w = s[d0 + 3][l];
    *(float4*)&eT[(l * 512 + k) * 64 + d0] = w;
  }
}

// ---------------- K2: argmin distance GEMM (+ coalesced xT emit) ----------------
// grid (8, 64): x = b-tile of 128, y = l. 256 threads: bg = t&15, kg = t>>4.
__global__ __launch_bounds__(256, 2) void kargmin(const float* __restrict__ x,
                                                  const float* __restrict__ eT,
                                                  const float* __restrict__ e2T,
                                                  int* __restrict__ idxout,
                                                  int* __restrict__ idxTout,
                                                  float* __restrict__ countsT,
                                                  float* __restrict__ xT) {
  const int l = blockIdx.y;
  const int b0 = blockIdx.x * 128;
  const int t = threadIdx.x;
  __shared__ float xs[128][68];
  __shared__ float es[128][68];
  __shared__ float e2s[128];
  float* xTl = xT + ((size_t)l * 1024 + b0) * 64;
  // strided x load (L2-absorbed) + coalesced transposed emit for kdw
#pragma unroll
  for (int i = 0; i < 32; ++i) {
    int e = t + i * 256;
    int bl = e >> 6, d = e & 63;
    float v = x[(b0 + bl) * 4096 + d * 64 + l];
    xs[bl][d] = v;
    xTl[e] = v;
  }
  const int bg = t & 15;
  const int kg = t >> 4;
  float bestv[8];
  int bestk[8];
#pragma unroll
  for (int i = 0; i < 8; ++i) { bestv[i] = 3.4e38f; bestk[i] = 0; }

  for (int chunk = 0; chunk < 4; ++chunk) {
    __syncthreads();  // xs ready (iter 0) / prev compute done before es overwrite
    const float* src = eT + (l * 512 + chunk * 128) * 64;
#pragma unroll
    for (int i = 0; i < 8; ++i) {
      int f4 = t + i * 256;            // 2048 float4 = 128x64
      int r = f4 >> 4;
      int c = (f4 & 15) * 4;
      *(float4*)&es[r][c] = *(const float4*)&src[f4 * 4];
    }
    if (t < 128) e2s[t] = e2T[l * 512 + chunk * 128 + t];
    __syncthreads();

    float acc[8][8];
#pragma unroll
    for (int i = 0; i < 8; ++i)
#pragma unroll
      for (int j = 0; j < 8; ++j) acc[i][j] = 0.f;

    for (int d4 = 0; d4 < 16; ++d4) {
      float4 xv[8], ev[8];
#pragma unroll
      for (int i = 0; i < 8; ++i) xv[i] = *(const float4*)&xs[bg + i * 16][d4 * 4];
#pragma unroll
      for (int j = 0; j < 8; ++j) ev[j] = *(const float4*)&es[kg + j * 16][d4 * 4];
#pragma unroll
      for (int i = 0; i < 8; ++i)
#pragma unroll
        for (int j = 0; j < 8; ++j) {
          acc[i][j] = fmaf(xv[i].x, ev[j].x, acc[i][j]);
          acc[i][j] = fmaf(xv[i].y, ev[j].y, acc[i][j]);
          acc[i][j] = fmaf(xv[i].z, ev[j].z, acc[i][j]);
          acc[i][j] = fmaf(xv[i].w, ev[j].w, acc[i][j]);
        }
    }
#pragma unroll
    for (int j = 0; j < 8; ++j) {
      int kk = kg + j * 16;
      int kglob = chunk * 128 + kk;
      float e2v = e2s[kk];
#pragma unroll
      for (int i = 0; i < 8; ++i) {
        float d2 = fmaf(-2.0f, acc[i][j], e2v);  // e2 - 2*xe, single rounding
        if (d2 < bestv[i] || (d2 == bestv[i] && kglob < bestk[i])) {
          bestv[i] = d2; bestk[i] = kglob;
        }
      }
    }
  }
  __syncthreads();
  // cross-kg reduction; reuse es (vals) and xs (k as float, exact for k<512)
  float* rv = &es[0][0];
  float* rkf = &xs[0][0];
#pragma unroll
  for (int i = 0; i < 8; ++i) {
    int bl = bg + i * 16;
    rv[bl * 16 + kg] = bestv[i];
    rkf[bl * 16 + kg] = (float)bestk[i];
  }
  __syncthreads();
  if (t < 128) {
    float bv = rv[t * 16];
    int bk = (int)rkf[t * 16];
#pragma unroll
    for (int g = 1; g < 16; ++g) {
      float v = rv[t * 16 + g];
      int kk = (int)rkf[t * 16 + g];
      if (v < bv || (v == bv && kk < bk)) { bv = v; bk = kk; }
    }
    idxout[(b0 + t) * 64 + l] = bk;
    idxTout[l * 1024 + b0 + t] = bk;
    unsafeAtomicAdd(&countsT[l * 512 + bk], 1.0f);  // integer counts: exact any order
  }
}

// ---------------- K3: dw_batch via LDS accumulation (coalesced xT reads) ----------------
// grid (2, 64): x = k-half, y = l. 1024 threads, 64KB LDS acc[256][64].
__global__ __launch_bounds__(1024) void kdw(const float* __restrict__ xT,
                                            const int* __restrict__ idxT,
                                            float* __restrict__ dwT) {
  const int l = blockIdx.y;
  const int kh = blockIdx.x * 256;
  const int t = threadIdx.x;
  __shared__ float acc[256 * 64];
#pragma unroll
  for (int i = 0; i < 16; ++i) acc[t + i * 1024] = 0.f;
  const int w = t >> 6, lane = t & 63;
  const int sidxreg = idxT[l * 1024 + w * 64 + lane];
  __syncthreads();
  const float* xTl = xT + (size_t)l * 65536;
#pragma unroll 4
  for (int j = 0; j < 64; ++j) {
    int k = __shfl(sidxreg, j, 64) - kh;  // wave-uniform
    if ((unsigned)k < 256u) {
      float v = xTl[(w * 64 + j) * 64 + lane];
      atomicAdd(&acc[(k << 6) + lane], v);  // ds_add_f32, 2 lanes/bank = free
    }
  }
  __syncthreads();
#pragma unroll
  for (int i = 0; i < 16; ++i) {
    int e = t + i * 1024;
    int k = e >> 6, d = e & 63;
    dwT[((size_t)(kh + k) * 64 + l) * 64 + d] = acc[e];
  }
}

// ---------------- K4: gather q, quantized, dense one-hot, loss ----------------
__global__ __launch_bounds__(256) void kgather(const float* __restrict__ x,
                                               const float* __restrict__ eT,
                                               const int* __restrict__ idxin,
                                               float* __restrict__ out_q,
                                               float* __restrict__ out_enc,
                                               double* __restrict__ lossAcc) {
  const int b = blockIdx.x;
  const int t = threadIdx.x;
  __shared__ float qb[64][68];
  __shared__ int lidx[64];
  __shared__ double wsumS[4];
  if (t < 64) lidx[t] = idxin[b * 64 + t];
  __syncthreads();
  const int l = t >> 2, qd = (t & 3) * 16;
  const int kse = lidx[l];
  const float* ep = eT + (l * 512 + kse) * 64 + qd;
#pragma unroll
  for (int j = 0; j < 4; ++j) {
    float4 v = *(const float4*)&ep[j * 4];
    qb[qd + j * 4 + 0][l] = v.x;
    qb[qd + j * 4 + 1][l] = v.y;
    qb[qd + j * 4 + 2][l] = v.z;
    qb[qd + j * 4 + 3][l] = v.w;
  }
  __syncthreads();
  float ls = 0.f;
  const float* xp = x + b * 4096;
  float* op = out_q + b * 4096;
#pragma unroll
  for (int i = 0; i < 4; ++i) {
    int f4 = t + i * 256;
    float4 xv = *(const float4*)&xp[f4 * 4];
    int d = f4 >> 4, l0 = (f4 & 15) * 4;
    float4 qv = *(const float4*)&qb[d][l0];
    float4 dv, ov;
    dv.x = qv.x - xv.x; dv.y = qv.y - xv.y; dv.z = qv.z - xv.z; dv.w = qv.w - xv.w;
    ov.x = xv.x + dv.x; ov.y = xv.y + dv.y; ov.z = xv.z + dv.z; ov.w = xv.w + dv.w;
    *(float4*)&op[f4 * 4] = ov;    // x + (q - x), replicated exactly
    ls = fmaf(dv.x, dv.x, ls); ls = fmaf(dv.y, dv.y, ls);
    ls = fmaf(dv.z, dv.z, ls); ls = fmaf(dv.w, dv.w, ls);
  }
  // dense one-hot row (128 KB per block, nontemporal streaming) — overwrites xT region
  float* encp = out_enc + (size_t)b * 32768;
#pragma unroll
  for (int i = 0; i < 32; ++i) {
    int f4 = t + i * 256;
    int e = f4 * 4;
    int k = e >> 6, l0 = e & 63;
    f32x4 v;
    v.x = (lidx[l0 + 0] == k) ? 1.f : 0.f;
    v.y = (lidx[l0 + 1] == k) ? 1.f : 0.f;
    v.z = (lidx[l0 + 2] == k) ? 1.f : 0.f;
    v.w = (lidx[l0 + 3] == k) ? 1.f : 0.f;
    __builtin_nontemporal_store(v, (f32x4*)&encp[e]);
  }
#pragma unroll
  for (int off = 32; off > 0; off >>= 1) ls += __shfl_down(ls, off, 64);
  if ((t & 63) == 0) wsumS[t >> 6] = (double)ls;
  __syncthreads();
  if (t == 0) unsafeAtomicAdd(lossAcc, wsumS[0] + wsumS[1] + wsumS[2] + wsumS[3]);
}

// ---------------- K5: cs + EMA (k=blk) | perplexity (blk>=512) + loss ----------------
__global__ __launch_bounds__(256) void kemafinal(const float* __restrict__ cluster,
                                                 const float* __restrict__ countsT,
                                                 const float* __restrict__ dw,
                                                 const float* __restrict__ emb,
                                                 const float* __restrict__ dwT,
                                                 const double* __restrict__ lossAcc,
                                                 float* __restrict__ out_cs,
                                                 float* __restrict__ out_emb,
                                                 float* __restrict__ out_dwb,
                                                 float* __restrict__ out_loss,
                                                 float* __restrict__ out_perp) {
  const int t = threadIdx.x;
  if (blockIdx.x >= 512) {
    const int l = blockIdx.x - 512;
    if (t < 64) {
      float s = 0.f;
#pragma unroll
      for (int i = 0; i < 8; ++i) {
        int k = t * 8 + i;
        float p = countsT[l * 512 + k] * (1.0f / 1024.0f);  // exact: /2^10
        s = __fadd_rn(s, __fmul_rn(p, logf(__fadd_rn(p, 1e-10f))));
      }
#pragma unroll
      for (int off = 32; off > 0; off >>= 1) s += __shfl_down(s, off, 64);
      if (t == 0) out_perp[l] = expf(-s) * (1.0f / 512.0f);
    }
    if (blockIdx.x == 512 && t == 64)
      out_loss[0] = (float)(lossAcc[0] / 4194304.0);  // mean over B*D*L
    return;
  }
  const int k = blockIdx.x;
  __shared__ float dwS[64][65];
  __shared__ float csS[64];
  __shared__ float nS;
  const float* sp = dwT + (size_t)k * 4096;
#pragma unroll
  for (int i = 0; i < 4; ++i) {
    int f4 = t + i * 256;
    float4 v = *(const float4*)&sp[f4 * 4];
    int l = f4 >> 4, d0 = (f4 & 15) * 4;
    dwS[l][d0] = v.x; dwS[l][d0 + 1] = v.y; dwS[l][d0 + 2] = v.z; dwS[l][d0 + 3] = v.w;
  }
  const float* cp = cluster + k * 64;
  if (t == 0) {
    float n = 0.f;
#pragma unroll
    for (int l = 0; l < 64; ++l) n = __fadd_rn(n, cp[l]);
    nS = __fadd_rn(n, 1e-06f);
  }
  __syncthreads();
  if (t < 64) {
    const float n = nS;
    const float denom = __fadd_rn(n, 0.000512f);  // n + K*EPS
    float t1 = __fadd_rn(cp[t], 1e-06f);
    float r = __fdiv_rn(t1, denom);
    float r2 = __fmul_rn(r, n);
    float cs = __fadd_rn(__fmul_rn(0.99f, r2), __fmul_rn(0.01f, countsT[t * 512 + k]));
    csS[t] = cs;
    out_cs[k * 64 + t] = cs;
  }
  __syncthreads();
  const int l = t & 63;
  const int dlane = t >> 6;
#pragma unroll
  for (int r = 0; r < 16; ++r) {
    int d = r * 4 + dlane;
    int g = d * 32768 + k * 64 + l;
    float batch = dwS[l][d];
    float buf = 0.99f * dw[g] + 0.01f * (batch / csS[l]);
    out_dwb[g] = buf;
    out_emb[g] = 0.99f * emb[g] + 0.01f * buf;
  }
}

extern "C" void kernel_launch(void* const* d_in, const int* in_sizes, int n_in,
                              void* d_out, int out_size, void* d_ws, size_t ws_size,
                              hipStream_t stream) {
  (void)in_sizes; (void)n_in; (void)out_size; (void)ws_size;
  const float* x    = (const float*)d_in[0];
  const float* emb  = (const float*)d_in[1];
  const float* dw   = (const float*)d_in[2];
  const float* clus = (const float*)d_in[3];

  float* out = (float*)d_out;
  float* out_q    = out;                 // 4194304
  float* out_enc  = out + 4194304;       // 33554432 (first 4.2M floats double as xT staging)
  float* out_loss = out + 37748736;      // 1
  float* out_perp = out + 37748737;      // 64
  float* out_emb  = out + 37748801;      // 2097152
  float* out_dwb  = out + 39845953;      // 2097152
  float* out_cs   = out + 41943105;      // 32768

  float* wsf = (float*)d_ws;
  float*  dwT     = wsf;                      // 2,097,152 floats (8 MB)
  float*  countsT = wsf + 2097152;            // 32768 (zeroed in K1)
  float*  eT      = wsf + 2129920;            // 2,097,152 (8 MB)
  float*  e2T     = wsf + 4227072;            // 32768
  int*    idxb    = (int*)(wsf + 4259840);    // 65536
  int*    idxT    = (int*)(wsf + 4325376);    // 65536
  double* lossA   = (double*)(wsf + 4390912); // 8 B (zeroed in K1); total ~17.56 MB

  float* xT = out_enc;  // 16 MB staging; consumed by kdw, overwritten by kgather

  ktransE<<<512, 256, 0, stream>>>(emb, eT, e2T, countsT, lossA);
  kargmin<<<dim3(8, 64), 256, 0, stream>>>(x, eT, e2T, idxb, idxT, countsT, xT);
  kdw<<<dim3(2, 64), 1024, 0, stream>>>(xT, idxT, dwT);
  kgather<<<1024, 256, 0, stream>>>(x, eT, idxb, out_q, out_enc, lossA);
  kemafinal<<<576, 256, 0, stream>>>(clus, countsT, dw, emb, dwT, lossA,
                                     out_cs, out_emb, out_dwb, out_loss, out_perp);
}

// Round 9
// 138.102 us; speedup vs baseline: 1.2797x; 1.2797x over previous
//
#include <hip/hip_runtime.h>

// Problem constants: B=1024, D=64, K=512, L=64 (h*w=8*8)
// x:        (B,D,L)   b*4096 + d*64 + l
// emb/dw:   (D,K,L)   d*32768 + k*64 + l
// eT:       (L,K,D)   (l*512 + k)*64 + d
// e2T:      (L,K)     l*512 + k
// countsT:  (L,K)     l*512 + k   (exact integer counts as float, via f32 atomics)
// dwT:      (K,L,D)   (k*64 + l)*64 + d
// idxb:     (B,L), idxT: (L,B)
// No xT staging: strided x reads are L2/L3-absorbed; round 8 proved the xT
// store stream thrashes L2 against eT re-reads and the enc write path.

typedef float f32x4 __attribute__((ext_vector_type(4)));

// ---------------- K1: emb transpose + e2 + zero counts/loss ----------------
__global__ __launch_bounds__(256) void ktransE(const float* __restrict__ emb,
                                               float* __restrict__ eT,
                                               float* __restrict__ e2T,
                                               float* __restrict__ countsT,
                                               double* __restrict__ lossAcc) {
  const int k = blockIdx.x;
  const int t = threadIdx.x;
  __shared__ float s[64][65];
#pragma unroll
  for (int i = 0; i < 16; ++i) {
    int e = t + i * 256;
    int d = e >> 6, l = e & 63;
    s[d][l] = emb[d * 32768 + k * 64 + l];
  }
  __syncthreads();
  if (t < 64) {
    float s2 = 0.f;
#pragma unroll
    for (int d = 0; d < 64; ++d) {
      float v = s[d][t];
      s2 = __fadd_rn(s2, __fmul_rn(v, v));  // round(v*v), sequential-d sum like ref
    }
    e2T[t * 512 + k] = s2;
    countsT[k * 64 + t] = 0.f;   // all 32768 entries zeroed across 512 blocks
  }
  if (k == 0 && t == 0) lossAcc[0] = 0.0;
#pragma unroll
  for (int i = 0; i < 4; ++i) {
    int j = t + i * 256;
    int l = j >> 4, d0 = (j & 15) * 4;
    float4 w;
    w.x = s[d0][l]; w.y = s[d0 + 1][l]; w.z = s[d0 + 2][l]; w.w = s[d0 + 3][l];
    *(float4*)&eT[(l * 512 + k) * 64 + d0] = w;
  }
}

// ---------------- K2: argmin distance GEMM ----------------
// grid (8, 64): x = b-tile of 128, y = l. 256 threads: bg = t&15, kg = t>>4.
// 4 chunks of 128 k-cols; LDS ~70 KB -> 2 blocks/CU.
__global__ __launch_bounds__(256, 2) void kargmin(const float* __restrict__ x,
                                                  const float* __restrict__ eT,
                                                  const float* __restrict__ e2T,
                                                  int* __restrict__ idxout,
                                                  int* __restrict__ idxTout,
                                                  float* __restrict__ countsT) {
  const int l = blockIdx.y;
  const int b0 = blockIdx.x * 128;
  const int t = threadIdx.x;
  __shared__ float xs[128][68];
  __shared__ float es[128][68];
  __shared__ float e2s[128];
  // strided x load (round-1/7-verified pattern): sectors L2-resident across l-blocks
#pragma unroll
  for (int i = 0; i < 32; ++i) {
    int e = t + i * 256;
    int bl = e >> 6, d = e & 63;
    xs[bl][d] = x[(b0 + bl) * 4096 + d * 64 + l];
  }
  const int bg = t & 15;
  const int kg = t >> 4;
  float bestv[8];
  int bestk[8];
#pragma unroll
  for (int i = 0; i < 8; ++i) { bestv[i] = 3.4e38f; bestk[i] = 0; }

  for (int chunk = 0; chunk < 4; ++chunk) {
    __syncthreads();  // xs ready (iter 0) / prev compute done before es overwrite
    const float* src = eT + (l * 512 + chunk * 128) * 64;
#pragma unroll
    for (int i = 0; i < 8; ++i) {
      int f4 = t + i * 256;            // 2048 float4 = 128x64
      int r = f4 >> 4;
      int c = (f4 & 15) * 4;
      *(float4*)&es[r][c] = *(const float4*)&src[f4 * 4];
    }
    if (t < 128) e2s[t] = e2T[l * 512 + chunk * 128 + t];
    __syncthreads();

    float acc[8][8];
#pragma unroll
    for (int i = 0; i < 8; ++i)
#pragma unroll
      for (int j = 0; j < 8; ++j) acc[i][j] = 0.f;

    for (int d4 = 0; d4 < 16; ++d4) {
      float4 xv[8], ev[8];
#pragma unroll
      for (int i = 0; i < 8; ++i) xv[i] = *(const float4*)&xs[bg + i * 16][d4 * 4];
#pragma unroll
      for (int j = 0; j < 8; ++j) ev[j] = *(const float4*)&es[kg + j * 16][d4 * 4];
#pragma unroll
      for (int i = 0; i < 8; ++i)
#pragma unroll
        for (int j = 0; j < 8; ++j) {
          acc[i][j] = fmaf(xv[i].x, ev[j].x, acc[i][j]);
          acc[i][j] = fmaf(xv[i].y, ev[j].y, acc[i][j]);
          acc[i][j] = fmaf(xv[i].z, ev[j].z, acc[i][j]);
          acc[i][j] = fmaf(xv[i].w, ev[j].w, acc[i][j]);
        }
    }
#pragma unroll
    for (int j = 0; j < 8; ++j) {
      int kk = kg + j * 16;
      int kglob = chunk * 128 + kk;
      float e2v = e2s[kk];
#pragma unroll
      for (int i = 0; i < 8; ++i) {
        float d2 = fmaf(-2.0f, acc[i][j], e2v);  // e2 - 2*xe, single rounding
        if (d2 < bestv[i] || (d2 == bestv[i] && kglob < bestk[i])) {
          bestv[i] = d2; bestk[i] = kglob;
        }
      }
    }
  }
  __syncthreads();
  // cross-kg reduction; reuse es (vals) and xs (k as float, exact for k<512)
  float* rv = &es[0][0];
  float* rkf = &xs[0][0];
#pragma unroll
  for (int i = 0; i < 8; ++i) {
    int bl = bg + i * 16;
    rv[bl * 16 + kg] = bestv[i];
    rkf[bl * 16 + kg] = (float)bestk[i];
  }
  __syncthreads();
  if (t < 128) {
    float bv = rv[t * 16];
    int bk = (int)rkf[t * 16];
#pragma unroll
    for (int g = 1; g < 16; ++g) {
      float v = rv[t * 16 + g];
      int kk = (int)rkf[t * 16 + g];
      if (v < bv || (v == bv && kk < bk)) { bv = v; bk = kk; }
    }
    idxout[(b0 + t) * 64 + l] = bk;
    idxTout[l * 1024 + b0 + t] = bk;
    unsafeAtomicAdd(&countsT[l * 512 + bk], 1.0f);  // integer counts: exact any order
  }
}

// ---------------- K3: role-split — dw-accumulate (256 blocks) + gather (1024 blocks) ----------------
__global__ __launch_bounds__(256) void kdwgather(const float* __restrict__ x,
                                                 const float* __restrict__ eT,
                                                 const int* __restrict__ idxb,
                                                 const int* __restrict__ idxT,
                                                 float* __restrict__ dwT,
                                                 float* __restrict__ out_q,
                                                 float* __restrict__ out_enc,
                                                 double* __restrict__ lossAcc) {
  const int t = threadIdx.x;
  __shared__ float SM[8192];   // 32 KB, reused per role
  if (blockIdx.x < 256) {
    // ---- dw-accumulate: block = (l = blk&63, kq = (blk>>6)*128) ----
    const int l = blockIdx.x & 63;
    const int kq = (blockIdx.x >> 6) * 128;
    float* acc = SM;  // 128 k x 64 d
#pragma unroll
    for (int i = 0; i < 32; ++i) acc[t + i * 256] = 0.f;
    const int w = t >> 6, lane = t & 63;
    __syncthreads();
    const int* idxl = idxT + l * 1024;
    for (int c = 0; c < 4; ++c) {
      const int base = w * 256 + c * 64;
      const int myidx = idxl[base + lane];
      // 8-wide batching: break the shfl->load->atomic dependent chain
      for (int jj = 0; jj < 64; jj += 8) {
        int ks[8]; float vs[8];
#pragma unroll
        for (int u = 0; u < 8; ++u) ks[u] = __shfl(myidx, jj + u, 64) - kq;  // wave-uniform
#pragma unroll
        for (int u = 0; u < 8; ++u)
          if ((unsigned)ks[u] < 128u)
            vs[u] = x[(size_t)(base + jj + u) * 4096 + lane * 64 + l];  // independent loads
#pragma unroll
        for (int u = 0; u < 8; ++u)
          if ((unsigned)ks[u] < 128u)
            atomicAdd(&acc[(ks[u] << 6) + lane], vs[u]);  // ds_add_f32, bank-clean
      }
    }
    __syncthreads();
#pragma unroll
    for (int i = 0; i < 32; ++i) {
      int e = t + i * 256;
      int k = e >> 6, d = e & 63;
      dwT[((size_t)(kq + k) * 64 + l) * 64 + d] = acc[e];
    }
  } else {
    // ---- gather/quantized/one-hot/loss: b = blk - 256 ----
    const int b = blockIdx.x - 256;
    float (*qb)[68] = (float (*)[68])SM;    // 64x68 = 4352
    int* lidx = (int*)(SM + 4352);          // 64
    double* wsumS = (double*)(SM + 4432);   // 8-aligned (float idx 4432 = byte 17728)
    if (t < 64) lidx[t] = idxb[b * 64 + t];
    __syncthreads();
    const int l = t >> 2, qd = (t & 3) * 16;
    const int kse = lidx[l];
    const float* ep = eT + (l * 512 + kse) * 64 + qd;
#pragma unroll
    for (int j = 0; j < 4; ++j) {
      float4 v = *(const float4*)&ep[j * 4];
      qb[qd + j * 4 + 0][l] = v.x;
      qb[qd + j * 4 + 1][l] = v.y;
      qb[qd + j * 4 + 2][l] = v.z;
      qb[qd + j * 4 + 3][l] = v.w;
    }
    __syncthreads();
    float ls = 0.f;
    const float* xp = x + b * 4096;
    float* op = out_q + b * 4096;
#pragma unroll
    for (int i = 0; i < 4; ++i) {
      int f4 = t + i * 256;
      float4 xv = *(const float4*)&xp[f4 * 4];
      int d = f4 >> 4, l0 = (f4 & 15) * 4;
      float4 qv = *(const float4*)&qb[d][l0];
      float4 dv, ov;
      dv.x = qv.x - xv.x; dv.y = qv.y - xv.y; dv.z = qv.z - xv.z; dv.w = qv.w - xv.w;
      ov.x = xv.x + dv.x; ov.y = xv.y + dv.y; ov.z = xv.z + dv.z; ov.w = xv.w + dv.w;
      *(float4*)&op[f4 * 4] = ov;    // x + (q - x), replicated exactly
      ls = fmaf(dv.x, dv.x, ls); ls = fmaf(dv.y, dv.y, ls);
      ls = fmaf(dv.z, dv.z, ls); ls = fmaf(dv.w, dv.w, ls);
    }
    // dense one-hot row (128 KB per block, nontemporal streaming)
    float* encp = out_enc + (size_t)b * 32768;
#pragma unroll
    for (int i = 0; i < 32; ++i) {
      int f4 = t + i * 256;
      int e = f4 * 4;
      int k = e >> 6, l0 = e & 63;
      f32x4 v;
      v.x = (lidx[l0 + 0] == k) ? 1.f : 0.f;
      v.y = (lidx[l0 + 1] == k) ? 1.f : 0.f;
      v.z = (lidx[l0 + 2] == k) ? 1.f : 0.f;
      v.w = (lidx[l0 + 3] == k) ? 1.f : 0.f;
      __builtin_nontemporal_store(v, (f32x4*)&encp[e]);
    }
#pragma unroll
    for (int off = 32; off > 0; off >>= 1) ls += __shfl_down(ls, off, 64);
    if ((t & 63) == 0) wsumS[t >> 6] = (double)ls;
    __syncthreads();
    if (t == 0) unsafeAtomicAdd(lossAcc, wsumS[0] + wsumS[1] + wsumS[2] + wsumS[3]);
  }
}

// ---------------- K4: cs + EMA (k=blk) | perplexity (blk>=512) + loss ----------------
__global__ __launch_bounds__(256) void kemafinal(const float* __restrict__ cluster,
                                                 const float* __restrict__ countsT,
                                                 const float* __restrict__ dw,
                                                 const float* __restrict__ emb,
                                                 const float* __restrict__ dwT,
                                                 const double* __restrict__ lossAcc,
                                                 float* __restrict__ out_cs,
                                                 float* __restrict__ out_emb,
                                                 float* __restrict__ out_dwb,
                                                 float* __restrict__ out_loss,
                                                 float* __restrict__ out_perp) {
  const int t = threadIdx.x;
  if (blockIdx.x >= 512) {
    const int l = blockIdx.x - 512;
    if (t < 64) {
      float s = 0.f;
#pragma unroll
      for (int i = 0; i < 8; ++i) {
        int k = t * 8 + i;
        float p = countsT[l * 512 + k] * (1.0f / 1024.0f);  // exact: /2^10
        s = __fadd_rn(s, __fmul_rn(p, logf(__fadd_rn(p, 1e-10f))));
      }
#pragma unroll
      for (int off = 32; off > 0; off >>= 1) s += __shfl_down(s, off, 64);
      if (t == 0) out_perp[l] = expf(-s) * (1.0f / 512.0f);
    }
    if (blockIdx.x == 512 && t == 64)
      out_loss[0] = (float)(lossAcc[0] / 4194304.0);  // mean over B*D*L
    return;
  }
  const int k = blockIdx.x;
  __shared__ float dwS[64][65];
  __shared__ float csS[64];
  __shared__ float nS;
  const float* sp = dwT + (size_t)k * 4096;
#pragma unroll
  for (int i = 0; i < 4; ++i) {
    int f4 = t + i * 256;
    float4 v = *(const float4*)&sp[f4 * 4];
    int l = f4 >> 4, d0 = (f4 & 15) * 4;
    dwS[l][d0] = v.x; dwS[l][d0 + 1] = v.y; dwS[l][d0 + 2] = v.z; dwS[l][d0 + 3] = v.w;
  }
  const float* cp = cluster + k * 64;
  if (t == 0) {
    float n = 0.f;
#pragma unroll
    for (int l = 0; l < 64; ++l) n = __fadd_rn(n, cp[l]);
    nS = __fadd_rn(n, 1e-06f);
  }
  __syncthreads();
  if (t < 64) {
    const float n = nS;
    const float denom = __fadd_rn(n, 0.000512f);  // n + K*EPS
    float t1 = __fadd_rn(cp[t], 1e-06f);
    float r = __fdiv_rn(t1, denom);
    float r2 = __fmul_rn(r, n);
    float cs = __fadd_rn(__fmul_rn(0.99f, r2), __fmul_rn(0.01f, countsT[t * 512 + k]));
    csS[t] = cs;
    out_cs[k * 64 + t] = cs;
  }
  __syncthreads();
  const int l = t & 63;
  const int dlane = t >> 6;
#pragma unroll
  for (int r = 0; r < 16; ++r) {
    int d = r * 4 + dlane;
    int g = d * 32768 + k * 64 + l;
    float batch = dwS[l][d];
    float buf = 0.99f * dw[g] + 0.01f * (batch / csS[l]);
    out_dwb[g] = buf;
    out_emb[g] = 0.99f * emb[g] + 0.01f * buf;
  }
}

extern "C" void kernel_launch(void* const* d_in, const int* in_sizes, int n_in,
                              void* d_out, int out_size, void* d_ws, size_t ws_size,
                              hipStream_t stream) {
  (void)in_sizes; (void)n_in; (void)out_size; (void)ws_size;
  const float* x    = (const float*)d_in[0];
  const float* emb  = (const float*)d_in[1];
  const float* dw   = (const float*)d_in[2];
  const float* clus = (const float*)d_in[3];

  float* out = (float*)d_out;
  float* out_q    = out;                 // 4194304
  float* out_enc  = out + 4194304;       // 33554432
  float* out_loss = out + 37748736;      // 1
  float* out_perp = out + 37748737;      // 64
  float* out_emb  = out + 37748801;      // 2097152
  float* out_dwb  = out + 39845953;      // 2097152
  float* out_cs   = out + 41943105;      // 32768

  float* wsf = (float*)d_ws;
  float*  dwT     = wsf;                      // 2,097,152 floats (8 MB)
  float*  countsT = wsf + 2097152;            // 32768 (zeroed in K1)
  float*  eT      = wsf + 2129920;            // 2,097,152 (8 MB)
  float*  e2T     = wsf + 4227072;            // 32768
  int*    idxb    = (int*)(wsf + 4259840);    // 65536
  int*    idxT    = (int*)(wsf + 4325376);    // 65536
  double* lossA   = (double*)(wsf + 4390912); // 8 B (zeroed in K1); total ~17.56 MB

  ktransE<<<512, 256, 0, stream>>>(emb, eT, e2T, countsT, lossA);
  kargmin<<<dim3(8, 64), 256, 0, stream>>>(x, eT, e2T, idxb, idxT, countsT);
  kdwgather<<<1280, 256, 0, stream>>>(x, eT, idxb, idxT, dwT, out_q, out_enc, lossA);
  kemafinal<<<576, 256, 0, stream>>>(clus, countsT, dw, emb, dwT, lossA,
                                     out_cs, out_emb, out_dwb, out_loss, out_perp);
}

// Round 10
// 133.735 us; speedup vs baseline: 1.3215x; 1.0327x over previous
//
#include <hip/hip_runtime.h>

// Problem constants: B=1024, D=64, K=512, L=64 (h*w=8*8)
// x:        (B,D,L)   b*4096 + d*64 + l
// emb/dw:   (D,K,L)   d*32768 + k*64 + l
// eT:       (L,K,D)   (l*512 + k)*64 + d
// e2T:      (L,K)     l*512 + k
// countsT:  (L,K)     l*512 + k   (exact integer counts as float, via f32 atomics)
// dwT:      (K,L,D)   (k*64 + l)*64 + d
// xT:       (L,B,D)   (l*1024 + b)*64 + d  -- in WS (503 MB available), written by K1.
//                     Round 8 lesson: xT must NOT be stored from inside kargmin nor
//                     aliased into the enc region. K1-produced xT was proven in round 3.
// idxb:     (B,L), idxT: (L,B)

typedef float f32x4 __attribute__((ext_vector_type(4)));

// ---------------- K1: fused emb transpose + e2 | x transpose | zero counts/loss ----------------
__global__ __launch_bounds__(256) void ktransAll(const float* __restrict__ emb,
                                                 const float* __restrict__ x,
                                                 float* __restrict__ eT,
                                                 float* __restrict__ e2T,
                                                 float* __restrict__ xT,
                                                 float* __restrict__ countsT,
                                                 double* __restrict__ lossAcc) {
  const int t = threadIdx.x;
  __shared__ float s[64][65];
  if (blockIdx.x < 512) {
    const int k = blockIdx.x;
#pragma unroll
    for (int i = 0; i < 16; ++i) {
      int e = t + i * 256;
      int d = e >> 6, l = e & 63;
      s[d][l] = emb[d * 32768 + k * 64 + l];
    }
    __syncthreads();
    if (t < 64) {
      float s2 = 0.f;
#pragma unroll
      for (int d = 0; d < 64; ++d) {
        float v = s[d][t];
        s2 = __fadd_rn(s2, __fmul_rn(v, v));  // round(v*v), sequential-d sum like ref
      }
      e2T[t * 512 + k] = s2;
      countsT[k * 64 + t] = 0.f;   // all 32768 entries zeroed across 512 blocks
    }
    if (k == 0 && t == 0) lossAcc[0] = 0.0;
#pragma unroll
    for (int i = 0; i < 4; ++i) {
      int j = t + i * 256;
      int l = j >> 4, d0 = (j & 15) * 4;
      float4 w;
      w.x = s[d0][l]; w.y = s[d0 + 1][l]; w.z = s[d0 + 2][l]; w.w = s[d0 + 3][l];
      *(float4*)&eT[(l * 512 + k) * 64 + d0] = w;
    }
  } else {
    const int b = blockIdx.x - 512;
    const float* xp = x + b * 4096;
#pragma unroll
    for (int i = 0; i < 4; ++i) {
      int f4 = t + i * 256;
      float4 v = *(const float4*)&xp[f4 * 4];
      int d = f4 >> 4, l0 = (f4 & 15) * 4;
      s[d][l0] = v.x; s[d][l0 + 1] = v.y; s[d][l0 + 2] = v.z; s[d][l0 + 3] = v.w;
    }
    __syncthreads();
#pragma unroll
    for (int i = 0; i < 4; ++i) {
      int j = t + i * 256;
      int l = j >> 4, d0 = (j & 15) * 4;
      float4 w;
      w.x = s[d0][l]; w.y = s[d0 + 1][l]; w.z = s[d0 + 2][l]; w.w = s[d0 + 3][l];
      *(float4*)&xT[((size_t)l * 1024 + b) * 64 + d0] = w;
    }
  }
}

// ---------------- K2: argmin distance GEMM (coalesced xT reads) ----------------
// grid (8, 64): x = b-tile of 128, y = l. 256 threads: bg = t&15, kg = t>>4.
// 4 chunks of 128 k-cols; LDS ~70 KB -> 2 blocks/CU (grid = 2/CU anyway).
__global__ __launch_bounds__(256, 2) void kargmin(const float* __restrict__ xT,
                                                  const float* __restrict__ eT,
                                                  const float* __restrict__ e2T,
                                                  int* __restrict__ idxout,
                                                  int* __restrict__ idxTout,
                                                  float* __restrict__ countsT) {
  const int l = blockIdx.y;
  const int b0 = blockIdx.x * 128;
  const int t = threadIdx.x;
  __shared__ float xs[128][68];
  __shared__ float es[128][68];
  __shared__ float e2s[128];
  const float* xsrc = xT + ((size_t)l * 1024 + b0) * 64;
#pragma unroll
  for (int i = 0; i < 8; ++i) {
    int f4 = t + i * 256;             // 2048 float4 = 128x64, fully coalesced
    int r = f4 >> 4;
    int c = (f4 & 15) * 4;
    *(float4*)&xs[r][c] = *(const float4*)&xsrc[f4 * 4];
  }
  const int bg = t & 15;
  const int kg = t >> 4;
  float bestv[8];
  int bestk[8];
#pragma unroll
  for (int i = 0; i < 8; ++i) { bestv[i] = 3.4e38f; bestk[i] = 0; }

  for (int chunk = 0; chunk < 4; ++chunk) {
    __syncthreads();  // xs ready (iter 0) / prev compute done before es overwrite
    const float* src = eT + (l * 512 + chunk * 128) * 64;
#pragma unroll
    for (int i = 0; i < 8; ++i) {
      int f4 = t + i * 256;            // 2048 float4 = 128x64
      int r = f4 >> 4;
      int c = (f4 & 15) * 4;
      *(float4*)&es[r][c] = *(const float4*)&src[f4 * 4];
    }
    if (t < 128) e2s[t] = e2T[l * 512 + chunk * 128 + t];
    __syncthreads();

    float acc[8][8];
#pragma unroll
    for (int i = 0; i < 8; ++i)
#pragma unroll
      for (int j = 0; j < 8; ++j) acc[i][j] = 0.f;

    for (int d4 = 0; d4 < 16; ++d4) {
      float4 xv[8], ev[8];
#pragma unroll
      for (int i = 0; i < 8; ++i) xv[i] = *(const float4*)&xs[bg + i * 16][d4 * 4];
#pragma unroll
      for (int j = 0; j < 8; ++j) ev[j] = *(const float4*)&es[kg + j * 16][d4 * 4];
#pragma unroll
      for (int i = 0; i < 8; ++i)
#pragma unroll
        for (int j = 0; j < 8; ++j) {
          acc[i][j] = fmaf(xv[i].x, ev[j].x, acc[i][j]);
          acc[i][j] = fmaf(xv[i].y, ev[j].y, acc[i][j]);
          acc[i][j] = fmaf(xv[i].z, ev[j].z, acc[i][j]);
          acc[i][j] = fmaf(xv[i].w, ev[j].w, acc[i][j]);
        }
    }
#pragma unroll
    for (int j = 0; j < 8; ++j) {
      int kk = kg + j * 16;
      int kglob = chunk * 128 + kk;
      float e2v = e2s[kk];
#pragma unroll
      for (int i = 0; i < 8; ++i) {
        float d2 = fmaf(-2.0f, acc[i][j], e2v);  // e2 - 2*xe, single rounding
        if (d2 < bestv[i] || (d2 == bestv[i] && kglob < bestk[i])) {
          bestv[i] = d2; bestk[i] = kglob;
        }
      }
    }
  }
  __syncthreads();
  // cross-kg reduction; reuse es (vals) and xs (k as float, exact for k<512)
  float* rv = &es[0][0];
  float* rkf = &xs[0][0];
#pragma unroll
  for (int i = 0; i < 8; ++i) {
    int bl = bg + i * 16;
    rv[bl * 16 + kg] = bestv[i];
    rkf[bl * 16 + kg] = (float)bestk[i];
  }
  __syncthreads();
  if (t < 128) {
    float bv = rv[t * 16];
    int bk = (int)rkf[t * 16];
#pragma unroll
    for (int g = 1; g < 16; ++g) {
      float v = rv[t * 16 + g];
      int kk = (int)rkf[t * 16 + g];
      if (v < bv || (v == bv && kk < bk)) { bv = v; bk = kk; }
    }
    idxout[(b0 + t) * 64 + l] = bk;
    idxTout[l * 1024 + b0 + t] = bk;
    unsafeAtomicAdd(&countsT[l * 512 + bk], 1.0f);  // integer counts: exact any order
  }
}

// ---------------- K3: role-split — dw-accumulate (256 blocks) + gather (1024 blocks) ----------------
__global__ __launch_bounds__(256) void kdwgather(const float* __restrict__ x,
                                                 const float* __restrict__ xT,
                                                 const float* __restrict__ eT,
                                                 const int* __restrict__ idxb,
                                                 const int* __restrict__ idxT,
                                                 float* __restrict__ dwT,
                                                 float* __restrict__ out_q,
                                                 float* __restrict__ out_enc,
                                                 double* __restrict__ lossAcc) {
  const int t = threadIdx.x;
  __shared__ float SM[8192];   // 32 KB, reused per role
  if (blockIdx.x < 256) {
    // ---- dw-accumulate: block = (l = blk&63, kq = (blk>>6)*128) ----
    const int l = blockIdx.x & 63;
    const int kq = (blockIdx.x >> 6) * 128;
    float* acc = SM;  // 128 k x 64 d
#pragma unroll
    for (int i = 0; i < 32; ++i) acc[t + i * 256] = 0.f;
    const int w = t >> 6, lane = t & 63;
    __syncthreads();
    const int* idxl = idxT + l * 1024;
    const float* xTl = xT + (size_t)l * 65536;
    for (int c = 0; c < 4; ++c) {
      const int base = w * 256 + c * 64;
      const int myidx = idxl[base + lane];
      // 8-wide batching + coalesced xT loads (256B per wave-load)
      for (int jj = 0; jj < 64; jj += 8) {
        int ks[8]; float vs[8];
#pragma unroll
        for (int u = 0; u < 8; ++u) ks[u] = __shfl(myidx, jj + u, 64) - kq;  // wave-uniform
#pragma unroll
        for (int u = 0; u < 8; ++u)
          if ((unsigned)ks[u] < 128u)
            vs[u] = xTl[(size_t)(base + jj + u) * 64 + lane];  // coalesced
#pragma unroll
        for (int u = 0; u < 8; ++u)
          if ((unsigned)ks[u] < 128u)
            atomicAdd(&acc[(ks[u] << 6) + lane], vs[u]);  // ds_add_f32, bank-clean
      }
    }
    __syncthreads();
#pragma unroll
    for (int i = 0; i < 32; ++i) {
      int e = t + i * 256;
      int k = e >> 6, d = e & 63;
      dwT[((size_t)(kq + k) * 64 + l) * 64 + d] = acc[e];
    }
  } else {
    // ---- gather/quantized/one-hot/loss: b = blk - 256 ----
    const int b = blockIdx.x - 256;
    float (*qb)[68] = (float (*)[68])SM;    // 64x68 = 4352
    int* lidx = (int*)(SM + 4352);          // 64
    double* wsumS = (double*)(SM + 4432);   // 8-aligned (float idx 4432 = byte 17728)
    if (t < 64) lidx[t] = idxb[b * 64 + t];
    __syncthreads();
    const int l = t >> 2, qd = (t & 3) * 16;
    const int kse = lidx[l];
    const float* ep = eT + (l * 512 + kse) * 64 + qd;
#pragma unroll
    for (int j = 0; j < 4; ++j) {
      float4 v = *(const float4*)&ep[j * 4];
      qb[qd + j * 4 + 0][l] = v.x;
      qb[qd + j * 4 + 1][l] = v.y;
      qb[qd + j * 4 + 2][l] = v.z;
      qb[qd + j * 4 + 3][l] = v.w;
    }
    __syncthreads();
    float ls = 0.f;
    const float* xp = x + b * 4096;
    float* op = out_q + b * 4096;
#pragma unroll
    for (int i = 0; i < 4; ++i) {
      int f4 = t + i * 256;
      float4 xv = *(const float4*)&xp[f4 * 4];
      int d = f4 >> 4, l0 = (f4 & 15) * 4;
      float4 qv = *(const float4*)&qb[d][l0];
      float4 dv, ov;
      dv.x = qv.x - xv.x; dv.y = qv.y - xv.y; dv.z = qv.z - xv.z; dv.w = qv.w - xv.w;
      ov.x = xv.x + dv.x; ov.y = xv.y + dv.y; ov.z = xv.z + dv.z; ov.w = xv.w + dv.w;
      *(float4*)&op[f4 * 4] = ov;    // x + (q - x), replicated exactly
      ls = fmaf(dv.x, dv.x, ls); ls = fmaf(dv.y, dv.y, ls);
      ls = fmaf(dv.z, dv.z, ls); ls = fmaf(dv.w, dv.w, ls);
    }
    // dense one-hot row (128 KB per block, nontemporal streaming)
    float* encp = out_enc + (size_t)b * 32768;
#pragma unroll
    for (int i = 0; i < 32; ++i) {
      int f4 = t + i * 256;
      int e = f4 * 4;
      int k = e >> 6, l0 = e & 63;
      f32x4 v;
      v.x = (lidx[l0 + 0] == k) ? 1.f : 0.f;
      v.y = (lidx[l0 + 1] == k) ? 1.f : 0.f;
      v.z = (lidx[l0 + 2] == k) ? 1.f : 0.f;
      v.w = (lidx[l0 + 3] == k) ? 1.f : 0.f;
      __builtin_nontemporal_store(v, (f32x4*)&encp[e]);
    }
#pragma unroll
    for (int off = 32; off > 0; off >>= 1) ls += __shfl_down(ls, off, 64);
    if ((t & 63) == 0) wsumS[t >> 6] = (double)ls;
    __syncthreads();
    if (t == 0) unsafeAtomicAdd(lossAcc, wsumS[0] + wsumS[1] + wsumS[2] + wsumS[3]);
  }
}

// ---------------- K4: cs + EMA (k=blk) | perplexity (blk>=512) + loss ----------------
__global__ __launch_bounds__(256) void kemafinal(const float* __restrict__ cluster,
                                                 const float* __restrict__ countsT,
                                                 const float* __restrict__ dw,
                                                 const float* __restrict__ emb,
                                                 const float* __restrict__ dwT,
                                                 const double* __restrict__ lossAcc,
                                                 float* __restrict__ out_cs,
                                                 float* __restrict__ out_emb,
                                                 float* __restrict__ out_dwb,
                                                 float* __restrict__ out_loss,
                                                 float* __restrict__ out_perp) {
  const int t = threadIdx.x;
  if (blockIdx.x >= 512) {
    const int l = blockIdx.x - 512;
    if (t < 64) {
      float s = 0.f;
#pragma unroll
      for (int i = 0; i < 8; ++i) {
        int k = t * 8 + i;
        float p = countsT[l * 512 + k] * (1.0f / 1024.0f);  // exact: /2^10
        s = __fadd_rn(s, __fmul_rn(p, logf(__fadd_rn(p, 1e-10f))));
      }
#pragma unroll
      for (int off = 32; off > 0; off >>= 1) s += __shfl_down(s, off, 64);
      if (t == 0) out_perp[l] = expf(-s) * (1.0f / 512.0f);
    }
    if (blockIdx.x == 512 && t == 64)
      out_loss[0] = (float)(lossAcc[0] / 4194304.0);  // mean over B*D*L
    return;
  }
  const int k = blockIdx.x;
  __shared__ float dwS[64][65];
  __shared__ float csS[64];
  __shared__ float nS;
  const float* sp = dwT + (size_t)k * 4096;
#pragma unroll
  for (int i = 0; i < 4; ++i) {
    int f4 = t + i * 256;
    float4 v = *(const float4*)&sp[f4 * 4];
    int l = f4 >> 4, d0 = (f4 & 15) * 4;
    dwS[l][d0] = v.x; dwS[l][d0 + 1] = v.y; dwS[l][d0 + 2] = v.z; dwS[l][d0 + 3] = v.w;
  }
  const float* cp = cluster + k * 64;
  if (t == 0) {
    float n = 0.f;
#pragma unroll
    for (int l = 0; l < 64; ++l) n = __fadd_rn(n, cp[l]);
    nS = __fadd_rn(n, 1e-06f);
  }
  __syncthreads();
  if (t < 64) {
    const float n = nS;
    const float denom = __fadd_rn(n, 0.000512f);  // n + K*EPS
    float t1 = __fadd_rn(cp[t], 1e-06f);
    float r = __fdiv_rn(t1, denom);
    float r2 = __fmul_rn(r, n);
    float cs = __fadd_rn(__fmul_rn(0.99f, r2), __fmul_rn(0.01f, countsT[t * 512 + k]));
    csS[t] = cs;
    out_cs[k * 64 + t] = cs;
  }
  __syncthreads();
  const int l = t & 63;
  const int dlane = t >> 6;
#pragma unroll
  for (int r = 0; r < 16; ++r) {
    int d = r * 4 + dlane;
    int g = d * 32768 + k * 64 + l;
    float batch = dwS[l][d];
    float buf = 0.99f * dw[g] + 0.01f * (batch / csS[l]);
    out_dwb[g] = buf;
    out_emb[g] = 0.99f * emb[g] + 0.01f * buf;
  }
}

extern "C" void kernel_launch(void* const* d_in, const int* in_sizes, int n_in,
                              void* d_out, int out_size, void* d_ws, size_t ws_size,
                              hipStream_t stream) {
  (void)in_sizes; (void)n_in; (void)out_size; (void)ws_size;
  const float* x    = (const float*)d_in[0];
  const float* emb  = (const float*)d_in[1];
  const float* dw   = (const float*)d_in[2];
  const float* clus = (const float*)d_in[3];

  float* out = (float*)d_out;
  float* out_q    = out;                 // 4194304
  float* out_enc  = out + 4194304;       // 33554432
  float* out_loss = out + 37748736;      // 1
  float* out_perp = out + 37748737;      // 64
  float* out_emb  = out + 37748801;      // 2097152
  float* out_dwb  = out + 39845953;      // 2097152
  float* out_cs   = out + 41943105;      // 32768

  // ws is ~503 MB (671.6 MB poison - 168 MB out); we use ~34.6 MB.
  float* wsf = (float*)d_ws;
  float*  dwT     = wsf;                      // 2,097,152 floats (8 MB)
  float*  countsT = wsf + 2097152;            // 32768 (zeroed in K1)
  float*  eT      = wsf + 2129920;            // 2,097,152 (8 MB)
  float*  e2T     = wsf + 4227072;            // 32768
  int*    idxb    = (int*)(wsf + 4259840);    // 65536
  int*    idxT    = (int*)(wsf + 4325376);    // 65536
  double* lossA   = (double*)(wsf + 4390912); // 8 B (zeroed in K1)
  float*  xT      = wsf + 4456448;            // 4,194,304 floats (16 MB), 256-aligned

  ktransAll<<<1536, 256, 0, stream>>>(emb, x, eT, e2T, xT, countsT, lossA);
  kargmin<<<dim3(8, 64), 256, 0, stream>>>(xT, eT, e2T, idxb, idxT, countsT);
  kdwgather<<<1280, 256, 0, stream>>>(x, xT, eT, idxb, idxT, dwT, out_q, out_enc, lossA);
  kemafinal<<<576, 256, 0, stream>>>(clus, countsT, dw, emb, dwT, lossA,
                                     out_cs, out_emb, out_dwb, out_loss, out_perp);
}

// Round 11
// 132.470 us; speedup vs baseline: 1.3341x; 1.0095x over previous
//
#include <hip/hip_runtime.h>

// Problem constants: B=1024, D=64, K=512, L=64 (h*w=8*8)
// x:        (B,D,L)   b*4096 + d*64 + l
// emb/dw:   (D,K,L)   d*32768 + k*64 + l
// eT:       (L,K,D)   (l*512 + k)*64 + d
// e2T:      (L,K)     l*512 + k
// countsT:  (L,K)     l*512 + k   (exact integer counts as float, via f32 atomics)
// dwT:      (K,L,D)   (k*64 + l)*64 + d
// xT:       (L,B,D)   (l*1024 + b)*64 + d  -- in WS, written by K1.
// idxb:     (B,L), idxT: (L,B)
// K2 grid is (l, b-tile) so all blocks sharing an eT slab co-locate on one XCD
// (linear id mod 8 = l mod 8 under round-robin dispatch) -> eT L2-local.

typedef float f32x4 __attribute__((ext_vector_type(4)));

// ---------------- K1: fused emb transpose + e2 | x transpose | zero counts/loss ----------------
__global__ __launch_bounds__(256) void ktransAll(const float* __restrict__ emb,
                                                 const float* __restrict__ x,
                                                 float* __restrict__ eT,
                                                 float* __restrict__ e2T,
                                                 float* __restrict__ xT,
                                                 float* __restrict__ countsT,
                                                 double* __restrict__ lossAcc) {
  const int t = threadIdx.x;
  __shared__ float s[64][65];
  if (blockIdx.x < 512) {
    const int k = blockIdx.x;
#pragma unroll
    for (int i = 0; i < 16; ++i) {
      int e = t + i * 256;
      int d = e >> 6, l = e & 63;
      s[d][l] = emb[d * 32768 + k * 64 + l];
    }
    __syncthreads();
    if (t < 64) {
      float s2 = 0.f;
#pragma unroll
      for (int d = 0; d < 64; ++d) {
        float v = s[d][t];
        s2 = __fadd_rn(s2, __fmul_rn(v, v));  // round(v*v), sequential-d sum like ref
      }
      e2T[t * 512 + k] = s2;
      countsT[k * 64 + t] = 0.f;   // all 32768 entries zeroed across 512 blocks
    }
    if (k == 0 && t == 0) lossAcc[0] = 0.0;
#pragma unroll
    for (int i = 0; i < 4; ++i) {
      int j = t + i * 256;
      int l = j >> 4, d0 = (j & 15) * 4;
      float4 w;
      w.x = s[d0][l]; w.y = s[d0 + 1][l]; w.z = s[d0 + 2][l]; w.w = s[d0 + 3][l];
      *(float4*)&eT[(l * 512 + k) * 64 + d0] = w;
    }
  } else {
    const int b = blockIdx.x - 512;
    const float* xp = x + b * 4096;
#pragma unroll
    for (int i = 0; i < 4; ++i) {
      int f4 = t + i * 256;
      float4 v = *(const float4*)&xp[f4 * 4];
      int d = f4 >> 4, l0 = (f4 & 15) * 4;
      s[d][l0] = v.x; s[d][l0 + 1] = v.y; s[d][l0 + 2] = v.z; s[d][l0 + 3] = v.w;
    }
    __syncthreads();
#pragma unroll
    for (int i = 0; i < 4; ++i) {
      int j = t + i * 256;
      int l = j >> 4, d0 = (j & 15) * 4;
      float4 w;
      w.x = s[d0][l]; w.y = s[d0 + 1][l]; w.z = s[d0 + 2][l]; w.w = s[d0 + 3][l];
      *(float4*)&xT[((size_t)l * 1024 + b) * 64 + d0] = w;
    }
  }
}

// ---------------- K2: argmin distance GEMM (coalesced xT reads, XCD-local eT) ----------------
// grid (64, 8): x = l, y = b-tile of 128. 256 threads: bg = t&15, kg = t>>4.
// 4 chunks of 128 k-cols; LDS ~70 KB -> 2 blocks/CU.
__global__ __launch_bounds__(256, 2) void kargmin(const float* __restrict__ xT,
                                                  const float* __restrict__ eT,
                                                  const float* __restrict__ e2T,
                                                  int* __restrict__ idxout,
                                                  int* __restrict__ idxTout,
                                                  float* __restrict__ countsT) {
  const int l = blockIdx.x;                // XCD = (y*64+x) % 8 = l % 8 -> slab-local
  const int b0 = blockIdx.y * 128;
  const int t = threadIdx.x;
  __shared__ float xs[128][68];
  __shared__ float es[128][68];
  __shared__ float e2s[128];
  const float* xsrc = xT + ((size_t)l * 1024 + b0) * 64;
#pragma unroll
  for (int i = 0; i < 8; ++i) {
    int f4 = t + i * 256;             // 2048 float4 = 128x64, fully coalesced
    int r = f4 >> 4;
    int c = (f4 & 15) * 4;
    *(float4*)&xs[r][c] = *(const float4*)&xsrc[f4 * 4];
  }
  const int bg = t & 15;
  const int kg = t >> 4;
  float bestv[8];
  int bestk[8];
#pragma unroll
  for (int i = 0; i < 8; ++i) { bestv[i] = 3.4e38f; bestk[i] = 0; }

  for (int chunk = 0; chunk < 4; ++chunk) {
    __syncthreads();  // xs ready (iter 0) / prev compute done before es overwrite
    const float* src = eT + (l * 512 + chunk * 128) * 64;
#pragma unroll
    for (int i = 0; i < 8; ++i) {
      int f4 = t + i * 256;            // 2048 float4 = 128x64
      int r = f4 >> 4;
      int c = (f4 & 15) * 4;
      *(float4*)&es[r][c] = *(const float4*)&src[f4 * 4];
    }
    if (t < 128) e2s[t] = e2T[l * 512 + chunk * 128 + t];
    __syncthreads();

    float acc[8][8];
#pragma unroll
    for (int i = 0; i < 8; ++i)
#pragma unroll
      for (int j = 0; j < 8; ++j) acc[i][j] = 0.f;

    for (int d4 = 0; d4 < 16; ++d4) {
      float4 xv[8], ev[8];
#pragma unroll
      for (int i = 0; i < 8; ++i) xv[i] = *(const float4*)&xs[bg + i * 16][d4 * 4];
#pragma unroll
      for (int j = 0; j < 8; ++j) ev[j] = *(const float4*)&es[kg + j * 16][d4 * 4];
#pragma unroll
      for (int i = 0; i < 8; ++i)
#pragma unroll
        for (int j = 0; j < 8; ++j) {
          acc[i][j] = fmaf(xv[i].x, ev[j].x, acc[i][j]);
          acc[i][j] = fmaf(xv[i].y, ev[j].y, acc[i][j]);
          acc[i][j] = fmaf(xv[i].z, ev[j].z, acc[i][j]);
          acc[i][j] = fmaf(xv[i].w, ev[j].w, acc[i][j]);
        }
    }
#pragma unroll
    for (int j = 0; j < 8; ++j) {
      int kk = kg + j * 16;
      int kglob = chunk * 128 + kk;
      float e2v = e2s[kk];
#pragma unroll
      for (int i = 0; i < 8; ++i) {
        float d2 = fmaf(-2.0f, acc[i][j], e2v);  // e2 - 2*xe, single rounding
        if (d2 < bestv[i] || (d2 == bestv[i] && kglob < bestk[i])) {
          bestv[i] = d2; bestk[i] = kglob;
        }
      }
    }
  }
  __syncthreads();
  // cross-kg reduction; reuse es (vals) and xs (k as float, exact for k<512)
  float* rv = &es[0][0];
  float* rkf = &xs[0][0];
#pragma unroll
  for (int i = 0; i < 8; ++i) {
    int bl = bg + i * 16;
    rv[bl * 16 + kg] = bestv[i];
    rkf[bl * 16 + kg] = (float)bestk[i];
  }
  __syncthreads();
  if (t < 128) {
    float bv = rv[t * 16];
    int bk = (int)rkf[t * 16];
#pragma unroll
    for (int g = 1; g < 16; ++g) {
      float v = rv[t * 16 + g];
      int kk = (int)rkf[t * 16 + g];
      if (v < bv || (v == bv && kk < bk)) { bv = v; bk = kk; }
    }
    idxout[(b0 + t) * 64 + l] = bk;
    idxTout[l * 1024 + b0 + t] = bk;
    unsafeAtomicAdd(&countsT[l * 512 + bk], 1.0f);  // integer counts: exact any order
  }
}

// ---------------- K3: role-split — dw-accumulate (256 blocks) + gather (1024 blocks) ----------------
__global__ __launch_bounds__(256) void kdwgather(const float* __restrict__ x,
                                                 const float* __restrict__ xT,
                                                 const float* __restrict__ eT,
                                                 const int* __restrict__ idxb,
                                                 const int* __restrict__ idxT,
                                                 float* __restrict__ dwT,
                                                 float* __restrict__ out_q,
                                                 float* __restrict__ out_enc,
                                                 double* __restrict__ lossAcc) {
  const int t = threadIdx.x;
  __shared__ float SM[8192];   // 32 KB, reused per role
  if (blockIdx.x < 256) {
    // ---- dw-accumulate: block = (l = blk&63, kq = (blk>>6)*128); XCD = l%8 ----
    const int l = blockIdx.x & 63;
    const int kq = (blockIdx.x >> 6) * 128;
    float* acc = SM;  // 128 k x 64 d
#pragma unroll
    for (int i = 0; i < 32; ++i) acc[t + i * 256] = 0.f;
    const int w = t >> 6, lane = t & 63;
    __syncthreads();
    const int* idxl = idxT + l * 1024;
    const float* xTl = xT + (size_t)l * 65536;
    for (int c = 0; c < 4; ++c) {
      const int base = w * 256 + c * 64;
      const int myidx = idxl[base + lane];
      // 8-wide batching + coalesced xT loads (256B per wave-load)
      for (int jj = 0; jj < 64; jj += 8) {
        int ks[8]; float vs[8];
#pragma unroll
        for (int u = 0; u < 8; ++u) ks[u] = __shfl(myidx, jj + u, 64) - kq;  // wave-uniform
#pragma unroll
        for (int u = 0; u < 8; ++u)
          if ((unsigned)ks[u] < 128u)
            vs[u] = xTl[(size_t)(base + jj + u) * 64 + lane];  // coalesced
#pragma unroll
        for (int u = 0; u < 8; ++u)
          if ((unsigned)ks[u] < 128u)
            atomicAdd(&acc[(ks[u] << 6) + lane], vs[u]);  // ds_add_f32, bank-clean
      }
    }
    __syncthreads();
#pragma unroll
    for (int i = 0; i < 32; ++i) {
      int e = t + i * 256;
      int k = e >> 6, d = e & 63;
      dwT[((size_t)(kq + k) * 64 + l) * 64 + d] = acc[e];
    }
  } else {
    // ---- gather/quantized/one-hot/loss: b = blk - 256 ----
    const int b = blockIdx.x - 256;
    float (*qb)[68] = (float (*)[68])SM;    // 64x68 = 4352
    int* lidx = (int*)(SM + 4352);          // 64
    double* wsumS = (double*)(SM + 4432);   // 8-aligned (float idx 4432 = byte 17728)
    if (t < 64) lidx[t] = idxb[b * 64 + t];
    __syncthreads();
    const int l = t >> 2, qd = (t & 3) * 16;
    const int kse = lidx[l];
    const float* ep = eT + (l * 512 + kse) * 64 + qd;
#pragma unroll
    for (int j = 0; j < 4; ++j) {
      float4 v = *(const float4*)&ep[j * 4];
      qb[qd + j * 4 + 0][l] = v.x;
      qb[qd + j * 4 + 1][l] = v.y;
      qb[qd + j * 4 + 2][l] = v.z;
      qb[qd + j * 4 + 3][l] = v.w;
    }
    __syncthreads();
    float ls = 0.f;
    const float* xp = x + b * 4096;
    float* op = out_q + b * 4096;
#pragma unroll
    for (int i = 0; i < 4; ++i) {
      int f4 = t + i * 256;
      float4 xv = *(const float4*)&xp[f4 * 4];
      int d = f4 >> 4, l0 = (f4 & 15) * 4;
      float4 qv = *(const float4*)&qb[d][l0];
      f32x4 ov;
      float dx = qv.x - xv.x, dy = qv.y - xv.y, dz = qv.z - xv.z, dw_ = qv.w - xv.w;
      ov.x = xv.x + dx; ov.y = xv.y + dy; ov.z = xv.z + dz; ov.w = xv.w + dw_;
      __builtin_nontemporal_store(ov, (f32x4*)&op[f4 * 4]);  // x + (q - x), streamed
      ls = fmaf(dx, dx, ls); ls = fmaf(dy, dy, ls);
      ls = fmaf(dz, dz, ls); ls = fmaf(dw_, dw_, ls);
    }
    // dense one-hot row (128 KB per block, nontemporal streaming)
    float* encp = out_enc + (size_t)b * 32768;
#pragma unroll
    for (int i = 0; i < 32; ++i) {
      int f4 = t + i * 256;
      int e = f4 * 4;
      int k = e >> 6, l0 = e & 63;
      f32x4 v;
      v.x = (lidx[l0 + 0] == k) ? 1.f : 0.f;
      v.y = (lidx[l0 + 1] == k) ? 1.f : 0.f;
      v.z = (lidx[l0 + 2] == k) ? 1.f : 0.f;
      v.w = (lidx[l0 + 3] == k) ? 1.f : 0.f;
      __builtin_nontemporal_store(v, (f32x4*)&encp[e]);
    }
#pragma unroll
    for (int off = 32; off > 0; off >>= 1) ls += __shfl_down(ls, off, 64);
    if ((t & 63) == 0) wsumS[t >> 6] = (double)ls;
    __syncthreads();
    if (t == 0) unsafeAtomicAdd(lossAcc, wsumS[0] + wsumS[1] + wsumS[2] + wsumS[3]);
  }
}

// ---------------- K4: cs + EMA (k=blk) | perplexity (blk>=512) + loss ----------------
__global__ __launch_bounds__(256) void kemafinal(const float* __restrict__ cluster,
                                                 const float* __restrict__ countsT,
                                                 const float* __restrict__ dw,
                                                 const float* __restrict__ emb,
                                                 const float* __restrict__ dwT,
                                                 const double* __restrict__ lossAcc,
                                                 float* __restrict__ out_cs,
                                                 float* __restrict__ out_emb,
                                                 float* __restrict__ out_dwb,
                                                 float* __restrict__ out_loss,
                                                 float* __restrict__ out_perp) {
  const int t = threadIdx.x;
  if (blockIdx.x >= 512) {
    const int l = blockIdx.x - 512;
    if (t < 64) {
      float s = 0.f;
#pragma unroll
      for (int i = 0; i < 8; ++i) {
        int k = t * 8 + i;
        float p = countsT[l * 512 + k] * (1.0f / 1024.0f);  // exact: /2^10
        s = __fadd_rn(s, __fmul_rn(p, logf(__fadd_rn(p, 1e-10f))));
      }
#pragma unroll
      for (int off = 32; off > 0; off >>= 1) s += __shfl_down(s, off, 64);
      if (t == 0) out_perp[l] = expf(-s) * (1.0f / 512.0f);
    }
    if (blockIdx.x == 512 && t == 64)
      out_loss[0] = (float)(lossAcc[0] / 4194304.0);  // mean over B*D*L
    return;
  }
  const int k = blockIdx.x;
  __shared__ float dwS[64][65];
  __shared__ float csS[64];
  __shared__ float nS;
  const float* sp = dwT + (size_t)k * 4096;
#pragma unroll
  for (int i = 0; i < 4; ++i) {
    int f4 = t + i * 256;
    float4 v = *(const float4*)&sp[f4 * 4];
    int l = f4 >> 4, d0 = (f4 & 15) * 4;
    dwS[l][d0] = v.x; dwS[l][d0 + 1] = v.y; dwS[l][d0 + 2] = v.z; dwS[l][d0 + 3] = v.w;
  }
  const float* cp = cluster + k * 64;
  if (t == 0) {
    float n = 0.f;
#pragma unroll
    for (int l = 0; l < 64; ++l) n = __fadd_rn(n, cp[l]);
    nS = __fadd_rn(n, 1e-06f);
  }
  __syncthreads();
  if (t < 64) {
    const float n = nS;
    const float denom = __fadd_rn(n, 0.000512f);  // n + K*EPS
    float t1 = __fadd_rn(cp[t], 1e-06f);
    float r = __fdiv_rn(t1, denom);
    float r2 = __fmul_rn(r, n);
    float cs = __fadd_rn(__fmul_rn(0.99f, r2), __fmul_rn(0.01f, countsT[t * 512 + k]));
    csS[t] = cs;
    out_cs[k * 64 + t] = cs;
  }
  __syncthreads();
  const int l = t & 63;
  const int dlane = t >> 6;
#pragma unroll
  for (int r = 0; r < 16; ++r) {
    int d = r * 4 + dlane;
    int g = d * 32768 + k * 64 + l;
    float batch = dwS[l][d];
    float buf = 0.99f * dw[g] + 0.01f * (batch / csS[l]);
    out_dwb[g] = buf;
    out_emb[g] = 0.99f * emb[g] + 0.01f * buf;
  }
}

extern "C" void kernel_launch(void* const* d_in, const int* in_sizes, int n_in,
                              void* d_out, int out_size, void* d_ws, size_t ws_size,
                              hipStream_t stream) {
  (void)in_sizes; (void)n_in; (void)out_size; (void)ws_size;
  const float* x    = (const float*)d_in[0];
  const float* emb  = (const float*)d_in[1];
  const float* dw   = (const float*)d_in[2];
  const float* clus = (const float*)d_in[3];

  float* out = (float*)d_out;
  float* out_q    = out;                 // 4194304
  float* out_enc  = out + 4194304;       // 33554432
  float* out_loss = out + 37748736;      // 1
  float* out_perp = out + 37748737;      // 64
  float* out_emb  = out + 37748801;      // 2097152
  float* out_dwb  = out + 39845953;      // 2097152
  float* out_cs   = out + 41943105;      // 32768

  float* wsf = (float*)d_ws;
  float*  dwT     = wsf;                      // 2,097,152 floats (8 MB)
  float*  countsT = wsf + 2097152;            // 32768 (zeroed in K1)
  float*  eT      = wsf + 2129920;            // 2,097,152 (8 MB)
  float*  e2T     = wsf + 4227072;            // 32768
  int*    idxb    = (int*)(wsf + 4259840);    // 65536
  int*    idxT    = (int*)(wsf + 4325376);    // 65536
  double* lossA   = (double*)(wsf + 4390912); // 8 B (zeroed in K1)
  float*  xT      = wsf + 4456448;            // 4,194,304 floats (16 MB), 256-aligned

  ktransAll<<<1536, 256, 0, stream>>>(emb, x, eT, e2T, xT, countsT, lossA);
  kargmin<<<dim3(64, 8), 256, 0, stream>>>(xT, eT, e2T, idxb, idxT, countsT);
  kdwgather<<<1280, 256, 0, stream>>>(x, xT, eT, idxb, idxT, dwT, out_q, out_enc, lossA);
  kemafinal<<<576, 256, 0, stream>>>(clus, countsT, dw, emb, dwT, lossA,
                                     out_cs, out_emb, out_dwb, out_loss, out_perp);
}